// Round 13
// baseline (56.814 us; speedup 1.0000x reference)
//
#include <hip/hip_runtime.h>

namespace {

typedef float v2f __attribute__((ext_vector_type(2)));

constexpr int kT   = 8;    // timesteps
constexpr int kB   = 256;  // batch
constexpr int kNQ  = 8;    // qubits per circuit
constexpr int kNB  = 8;    // blocks
constexpr int kD   = 64;   // features
constexpr int kNL  = 2;    // quantum layers
constexpr int kCirc = kT * kNB;        // 64 circuits per layer
constexpr int kGates = 2 * kNQ;        // 16 gate slots per circuit
constexpr int kGateF = 8;

// ---------------- Rot-gate precompute ----------------
// slots (d=0,w=0..7) and (d=1,w=0..5): full 2x2 complex gate (8 floats)
// slots (d=1,w=6..7): Hermitian h = g^dag Z g stored as (a, Re b, Im b, 0...)
__global__ void precompute_gates(const float* __restrict__ theta, float* __restrict__ gt) {
    int i = blockIdx.x * blockDim.x + threadIdx.x;
    if (i >= kNL * kCirc * kGates) return;
    int g = i & 15;
    int c = (i >> 4) & 63;
    int l = i >> 10;
    int t = c >> 3, u = c & 7;
    int d = g >> 3, w = g & 7;
    const float* th = theta + ((((t * kNL + l) * kNB + u) * 2 + d) * kNQ + w) * 3;
    float phi = th[0], tht = th[1], omg = th[2];
    float st, ct, sp, cp, sm, cm;
    __sincosf(0.5f * tht, &st, &ct);
    __sincosf(0.5f * (phi + omg), &sp, &cp);
    __sincosf(0.5f * (phi - omg), &sm, &cm);
    const float u00r =  ct * cp, u00i = -ct * sp;
    const float u01r = -st * cm, u01i = -st * sm;
    const float u10r =  st * cm, u10i = -st * sm;
    const float u11r =  ct * cp, u11i =  ct * sp;
    float* o = gt + i * kGateF;
    if (d == 1 && w >= 6) {
        // h = g^dag Z g: h00 = |u00|^2-|u10|^2, h01 = conj(u00)u01 - conj(u10)u11
        o[0] = (u00r * u00r + u00i * u00i) - (u10r * u10r + u10i * u10i);
        o[1] = (u00r * u01r + u00i * u01i) - (u10r * u11r + u10i * u11i);
        o[2] = (u00r * u01i - u00i * u01r) - (u10r * u11i - u10i * u11r);
        o[3] = 0.0f; o[4] = 0.0f; o[5] = 0.0f; o[6] = 0.0f; o[7] = 0.0f;
    } else {
        o[0] = u00r;  o[1] = u00i;
        o[2] = u01r;  o[3] = u01i;
        o[4] = u10r;  o[5] = u10i;
        o[6] = u11r;  o[7] = u11i;
    }
}

// ---------------- fast sincos (half-angle folded into revolution scale) ----------------
// v_sin/v_cos take REVOLUTIONS; our angles give |rev| < 0.5 (inputs) / < 0.08
// (expvals), far inside the +-256 valid range -> skip libm range reduction.
__device__ __forceinline__ void fastsc(float a, float& s, float& c) {
#if __has_builtin(__builtin_amdgcn_sinf) && __has_builtin(__builtin_amdgcn_cosf)
    const float r = a * 0.07957747154594767f;   // 0.5 / (2*pi)
    s = __builtin_amdgcn_sinf(r);
    c = __builtin_amdgcn_cosf(r);
#else
    __sincosf(0.5f * a, &s, &c);
#endif
}

// ---------------- shuffle backends ----------------
template <int CTRL>
__device__ __forceinline__ float f_dpp(float x) {
    return __builtin_bit_cast(float, __builtin_amdgcn_update_dpp(
        0, __builtin_bit_cast(int, x), CTRL, 0xF, 0xF, true));
}
constexpr int kDppXor1 = 0xB1;   // quad_perm [1,0,3,2]  = lane^1
constexpr int kDppXor2 = 0x4E;   // quad_perm [2,3,0,1]  = lane^2
constexpr int kDppXor8 = 0x128;  // row_ror:8 (16-lane row) = lane^8  [validated r7/r8]

// partner fetch at lane distance 1<<MODE: 0,1,3 via DPP (VALU); 2,4,5 via shfl (DS).
// permlane16/32_swap is BANNED: 3 failed rounds (r3, r6, r10).
template <int MODE>
__device__ __forceinline__ float lane_partner(float x) {
    if constexpr (MODE == 0) return f_dpp<kDppXor1>(x);
    else if constexpr (MODE == 1) return f_dpp<kDppXor2>(x);
    else if constexpr (MODE == 3) return f_dpp<kDppXor8>(x);
    else if constexpr (MODE == 2) return __shfl_xor(x, 4, 64);
    else if constexpr (MODE == 4) return __shfl_xor(x, 16, 64);
    else return __shfl_xor(x, 32, 64);
}
template <int MODE>
__device__ __forceinline__ v2f partner2(v2f v) {
    v2f r;
    r.x = lane_partner<MODE>(v.x);
    r.y = lane_partner<MODE>(v.y);
    return r;
}

// per-wire packed trig for both samples
template <int W>
__device__ __forceinline__ void trig(const float (&ang)[2][8], v2f& cs, v2f& sn) {
    float s0, c0, s1, c1;
    fastsc(ang[0][W], s0, c0);
    fastsc(ang[1][W], s1, c1);
    cs.x = c0; cs.y = c1;
    sn.x = s0; sn.y = s1;
}

// selected single spinor component: comp[x] of (RY(ang) then d0-Rot gate gp)
// coeffs selected per lane first (scalar cndmask), then 4 pk-fma.
__device__ __forceinline__ void spinor_sel(const v2f& cs, const v2f& sn,
                                           const float* __restrict__ gp, int x,
                                           v2f& r, v2f& i) {
    const float cAr = x ? gp[4] : gp[0], cAi = x ? gp[5] : gp[1];
    const float cBr = x ? gp[6] : gp[2], cBi = x ? gp[7] : gp[3];
    r = cAr * cs + cBr * sn;
    i = cAi * cs + cBi * sn;
}
// both components, ordered (comp[x], comp[1-x])
__device__ __forceinline__ void spinor_both(const v2f& cs, const v2f& sn,
                                            const float* __restrict__ gp, int x,
                                            v2f& r0, v2f& i0, v2f& r1, v2f& i1) {
    spinor_sel(cs, sn, gp, x, r0, i0);
    spinor_sel(cs, sn, gp, x ^ 1, r1, i1);
}

// ---------------- gate helper (2 packed samples, 4 amps/lane) ----------------
// amp index k = (lane<<2)|reg; wire w -> index bit 7-w.
// wires 0..5 -> lane bits 5..0; wires 6,7 -> reg bits 1,0 (folded as Hermitian forms).
template <int MODE>
__device__ __forceinline__ void gate_p(v2f (&re)[4], v2f (&im)[4], int bit,
                                       const float* __restrict__ gp) {
    const float aR = bit ? gp[6] : gp[0];
    const float aI = bit ? gp[7] : gp[1];
    const float bR = bit ? gp[4] : gp[2];
    const float bI = bit ? gp[5] : gp[3];
#pragma unroll
    for (int r = 0; r < 4; ++r) {
        const v2f pre = partner2<MODE>(re[r]);
        const v2f pim = partner2<MODE>(im[r]);
        const v2f mre = re[r], mim = im[r];
        re[r] = aR * mre - aI * mim + bR * pre - bI * pim;   // v_pk_fma_f32 chain
        im[r] = aR * mim + aI * mre + bR * pim + bI * pre;
    }
}

// ---------------- one circuit sim: 2 packed samples, 3 Walsh streams out ----------------
// State after AngleEmbedding + depth-0 Rot + CNOT-ring1 built directly as a permuted
// spinor product; depth-1 Rot gates on lane-bit wires; reg-bit wires (6,7) folded as
// Hermitian quadratic forms; CNOT-ring2 folded into Walsh parities of the reduction.
__device__ __forceinline__ void sim2p(const float (&ang)[2][8],
                                      const float* __restrict__ g0,
                                      const float* __restrict__ g1,
                                      int lane, const v2f (&sv)[6],
                                      v2f& WPo, v2f& WR1o, v2f& WR0o) {
    const int l0 = lane & 1,        l1 = (lane >> 1) & 1, l2 = (lane >> 2) & 1;
    const int l3 = (lane >> 3) & 1, l4 = (lane >> 4) & 1, l5 = (lane >> 5) & 1;

    // ring1 inverse bit map (x = pre-ring1 wire bits; (lane,reg) = post-ring1):
    //  x0=l5^r0  x1=l5^l4^r0  x2=l4^l3  x3=l3^l2  x4=l2^l1  x5=l1^l0
    //  x6=l0^r1  x7=r1^r0
    const int x2 = l4 ^ l3, x3 = l3 ^ l2, x4 = l2 ^ l1, x5 = l1 ^ l0;

    v2f re[4], im[4];
    {
        // --- L = s2[x2]*s3[x3]*s4[x4]*s5[x5]: selected components only ---
        v2f cs, sn, ar, ai, br, bi;
        trig<2>(ang, cs, sn); spinor_sel(cs, sn, g0 + 2 * kGateF, x2, ar, ai);
        trig<3>(ang, cs, sn); spinor_sel(cs, sn, g0 + 3 * kGateF, x3, br, bi);
        const v2f t1r = ar * br - ai * bi, t1i = ar * bi + ai * br;
        trig<4>(ang, cs, sn); spinor_sel(cs, sn, g0 + 4 * kGateF, x4, ar, ai);
        trig<5>(ang, cs, sn); spinor_sel(cs, sn, g0 + 5 * kGateF, x5, br, bi);
        const v2f t2r = ar * br - ai * bi, t2i = ar * bi + ai * br;
        const v2f Lr = t1r * t2r - t1i * t2i, Li = t1r * t2i + t1i * t2r;

        // --- LQ(r0) = L * s0[l5^r0] * s1[l5^l4^r0] ---
        v2f a0r, a0i, a1r, a1i, b0r, b0i, b1r, b1i;
        trig<0>(ang, cs, sn); spinor_both(cs, sn, g0 + 0 * kGateF, l5,      a0r, a0i, a1r, a1i);
        trig<1>(ang, cs, sn); spinor_both(cs, sn, g0 + 1 * kGateF, l5 ^ l4, b0r, b0i, b1r, b1i);
        const v2f Q0r = a0r * b0r - a0i * b0i, Q0i = a0r * b0i + a0i * b0r;
        const v2f Q1r = a1r * b1r - a1i * b1i, Q1i = a1r * b1i + a1i * b1r;
        const v2f LQ0r = Lr * Q0r - Li * Q0i, LQ0i = Lr * Q0i + Li * Q0r;
        const v2f LQ1r = Lr * Q1r - Li * Q1i, LQ1i = Lr * Q1i + Li * Q1r;

        // --- amp[r] = LQ(r0) * R(r1)*S(r1^r0);  R = s6[l0^r1], S = s7 ---
        v2f R0r, R0i, R1r, R1i, S0r, S0i, S1r, S1i;
        trig<6>(ang, cs, sn); spinor_both(cs, sn, g0 + 6 * kGateF, l0, R0r, R0i, R1r, R1i);
        trig<7>(ang, cs, sn); spinor_both(cs, sn, g0 + 7 * kGateF, 0,  S0r, S0i, S1r, S1i);
        v2f RSr[4], RSi[4];
        RSr[0] = R0r * S0r - R0i * S0i;  RSi[0] = R0r * S0i + R0i * S0r;  // r=0: R0*S0
        RSr[1] = R0r * S1r - R0i * S1i;  RSi[1] = R0r * S1i + R0i * S1r;  // r=1: R0*S1
        RSr[2] = R1r * S1r - R1i * S1i;  RSi[2] = R1r * S1i + R1i * S1r;  // r=2: R1*S1
        RSr[3] = R1r * S0r - R1i * S0i;  RSi[3] = R1r * S0i + R1i * S0r;  // r=3: R1*S0
        re[0] = LQ0r * RSr[0] - LQ0i * RSi[0]; im[0] = LQ0r * RSi[0] + LQ0i * RSr[0];
        re[1] = LQ1r * RSr[1] - LQ1i * RSi[1]; im[1] = LQ1r * RSi[1] + LQ1i * RSr[1];
        re[2] = LQ0r * RSr[2] - LQ0i * RSi[2]; im[2] = LQ0r * RSi[2] + LQ0i * RSr[2];
        re[3] = LQ1r * RSr[3] - LQ1i * RSi[3]; im[3] = LQ1r * RSi[3] + LQ1i * RSr[3];
    }

    // --- depth-1 Rot gates on lane-bit wires (wire w on lane bit 5-w) ---
    gate_p<5>(re, im, l5, g1 + 0 * kGateF);     // wire0: xor32 (shfl)
    gate_p<4>(re, im, l4, g1 + 1 * kGateF);     // wire1: xor16 (shfl)
    gate_p<3>(re, im, l3, g1 + 2 * kGateF);     // wire2: xor8 (DPP row_ror:8)
    gate_p<2>(re, im, l2, g1 + 3 * kGateF);     // wire3: xor4 (shfl)
    gate_p<1>(re, im, l1, g1 + 4 * kGateF);     // wire4: xor2 (DPP)
    gate_p<0>(re, im, l0, g1 + 5 * kGateF);     // wire5: xor1 (DPP)

    // --- reg-bit wires via Hermitian forms (packed) ---
    const v2f p0 = re[0] * re[0] + im[0] * im[0];
    const v2f p1 = re[1] * re[1] + im[1] * im[1];
    const v2f p2 = re[2] * re[2] + im[2] * im[2];
    const v2f p3 = re[3] * re[3] + im[3] * im[3];
    v2f P = (p0 + p1) + (p2 + p3);
    const float* h6 = g1 + 6 * kGateF;
    const float* h7 = g1 + 7 * kGateF;
    const v2f z1r = re[0] * re[2] + im[0] * im[2] + re[1] * re[3] + im[1] * im[3];
    const v2f z1i = re[0] * im[2] - im[0] * re[2] + re[1] * im[3] - im[1] * re[3];
    v2f R1 = h6[0] * ((p0 + p1) - (p2 + p3)) + 2.0f * (h6[1] * z1r - h6[2] * z1i);
    const v2f z0r = re[0] * re[1] + im[0] * im[1] + re[2] * re[3] + im[2] * im[3];
    const v2f z0i = re[0] * im[1] - im[0] * re[1] + re[2] * im[3] - im[2] * re[3];
    v2f R0 = h7[0] * ((p0 - p1) + (p2 - p3)) + 2.0f * (h7[1] * z0r - h7[2] * z0i);

    // --- ring2 folded into Walsh parities: full WHT butterfly, W[m] at lane m ---
    // per level: v' = partner + sv[q] * v  (sv = packed ±1 from lane bit q)
#pragma unroll
    for (int st = 0; st < 3; ++st) {
        v2f v = (st == 0) ? P : (st == 1) ? R1 : R0;
        v2f d;
        d = partner2<0>(v); v = d + sv[0] * v;
        d = partner2<1>(v); v = d + sv[1] * v;
        d = partner2<2>(v); v = d + sv[2] * v;
        d = partner2<3>(v); v = d + sv[3] * v;
        d = partner2<4>(v); v = d + sv[4] * v;
        d = partner2<5>(v); v = d + sv[5] * v;
        if (st == 0) P = v; else if (st == 1) R1 = v; else R0 = v;
    }
    WPo = P; WR1o = R1; WR0o = R0;
}

// scatter the 8 expvals (E_w = Walsh coeffs at fixed lanes), element stride STRIDE
// masks: E0:R1@10  E1:R0@5  E2:P@40  E3:P@20  E4:P@42  E5:P@21  E6:R1@42  E7:R0@21
template <int STRIDE, typename PT>
__device__ __forceinline__ void scatter_ev(PT e, int lane, float P, float R1, float R0) {
    if (lane == 10) e[0 * STRIDE] = R1;
    if (lane ==  5) e[1 * STRIDE] = R0;
    if (lane == 40) e[2 * STRIDE] = P;
    if (lane == 20) e[3 * STRIDE] = P;
    if (lane == 42) { e[4 * STRIDE] = P; e[6 * STRIDE] = R1; }
    if (lane == 21) { e[5 * STRIDE] = P; e[7 * STRIDE] = R0; }
}

// ---------------- fused both-layer kernel ----------------
// block = 512 threads = 8 waves = the 8 circuits of one (t, sample-pair);
// 2 packed samples per wave; layer-0 results exchanged through 512 B of LDS.
// exch layout [sample][wire][block]: phase-1 angle gather = 2x float4 broadcast reads.
__global__ __launch_bounds__(512, 4) void fused_kernel(const float* __restrict__ x,
                                                       const float* __restrict__ gt,
                                                       float* __restrict__ out) {
    const int widx = __builtin_amdgcn_readfirstlane(threadIdx.x >> 6);  // circuit u
    const int lane = threadIdx.x & 63;
    const int tt = blockIdx.x >> 7;          // timestep
    const int b0 = (blockIdx.x & 127) << 1;  // first sample of pair

    __shared__ float exch[2][8][8];          // [sample][wire][block]

    v2f sv[6];
#pragma unroll
    for (int q = 0; q < 6; ++q) {
        const float s = ((lane >> q) & 1) ? -1.0f : 1.0f;
        sv[q].x = s; sv[q].y = s;
    }

    const int c = tt * kNB + widx;
    v2f WP, WR1, WR0;
    float ang[2][8];

    // ---- phase 0: layer-0 circuit (t, widx), samples b0, b0+1 ----
    {
        const float* g0 = gt + (size_t)c * kGates * kGateF;
        const float* g1 = g0 + 8 * kGateF;
#pragma unroll
        for (int s = 0; s < 2; ++s) {
            const float* ab = x + (((b0 + s) * kT + tt) * kD + widx * kNQ);
#pragma unroll
            for (int w = 0; w < 8; ++w) ang[s][w] = ab[w];
        }
        sim2p(ang, g0, g1, lane, sv, WP, WR1, WR0);
        scatter_ev<8>(&exch[0][0][widx], lane, WP.x, WR1.x, WR0.x);
        scatter_ev<8>(&exch[1][0][widx], lane, WP.y, WR1.y, WR0.y);
    }
    __syncthreads();
    // ---- phase 1: layer-1 circuit (t, widx) gathers feature widx of every block ----
    {
        const float* g0 = gt + (size_t)(kCirc + c) * kGates * kGateF;
        const float* g1 = g0 + 8 * kGateF;
#pragma unroll
        for (int s = 0; s < 2; ++s) {
            const float4 v0 = *reinterpret_cast<const float4*>(&exch[s][widx][0]);
            const float4 v1 = *reinterpret_cast<const float4*>(&exch[s][widx][4]);
            ang[s][0] = v0.x; ang[s][1] = v0.y; ang[s][2] = v0.z; ang[s][3] = v0.w;
            ang[s][4] = v1.x; ang[s][5] = v1.y; ang[s][6] = v1.z; ang[s][7] = v1.w;
        }
        sim2p(ang, g0, g1, lane, sv, WP, WR1, WR0);
        scatter_ev<1>(out + (((b0 + 0) * kT + tt) * kD + widx * kNQ), lane, WP.x, WR1.x, WR0.x);
        scatter_ev<1>(out + (((b0 + 1) * kT + tt) * kD + widx * kNQ), lane, WP.y, WR1.y, WR0.y);
    }
}

}  // namespace

extern "C" void kernel_launch(void* const* d_in, const int* in_sizes, int n_in,
                              void* d_out, int out_size, void* d_ws, size_t ws_size,
                              hipStream_t stream) {
    const float* x     = (const float*)d_in[0];   // (B, T, D) fp32
    const float* theta = (const float*)d_in[1];   // (T, NL, NB, DEPTH, NQ, 3) fp32
    float* out = (float*)d_out;                   // (B, T, D) fp32

    float* gt = (float*)d_ws;                     // gate table: 2*64*16*8 floats (64 KB)

    precompute_gates<<<(kNL * kCirc * kGates + 255) / 256, 256, 0, stream>>>(theta, gt);
    // 8 timesteps x 128 sample-pairs; 512 threads = 8 circuits x 2 packed samples/wave
    fused_kernel<<<kT * (kB / 2), 512, 0, stream>>>(x, gt, out);
}

// Round 14
// 35.122 us; speedup vs baseline: 1.6176x; 1.6176x over previous
//
#include <hip/hip_runtime.h>

namespace {

typedef float v2f __attribute__((ext_vector_type(2)));

constexpr int kT   = 8;    // timesteps
constexpr int kB   = 256;  // batch
constexpr int kNQ  = 8;    // qubits per circuit
constexpr int kNB  = 8;    // blocks
constexpr int kD   = 64;   // features
constexpr int kNL  = 2;    // quantum layers
constexpr int kCirc = kT * kNB;        // 64 circuits per layer
constexpr int kGates = 2 * kNQ;        // 16 gate slots per circuit
constexpr int kGateF = 8;

// ---------------- Rot-gate precompute ----------------
// slots (d=0,w=0..7) and (d=1,w=0..5): full 2x2 complex gate (8 floats)
// slots (d=1,w=6..7): Hermitian h = g^dag Z g stored as (a, Re b, Im b, 0...)
__global__ void precompute_gates(const float* __restrict__ theta, float* __restrict__ gt) {
    int i = blockIdx.x * blockDim.x + threadIdx.x;
    if (i >= kNL * kCirc * kGates) return;
    int g = i & 15;
    int c = (i >> 4) & 63;
    int l = i >> 10;
    int t = c >> 3, u = c & 7;
    int d = g >> 3, w = g & 7;
    const float* th = theta + ((((t * kNL + l) * kNB + u) * 2 + d) * kNQ + w) * 3;
    float phi = th[0], tht = th[1], omg = th[2];
    float st, ct, sp, cp, sm, cm;
    __sincosf(0.5f * tht, &st, &ct);
    __sincosf(0.5f * (phi + omg), &sp, &cp);
    __sincosf(0.5f * (phi - omg), &sm, &cm);
    const float u00r =  ct * cp, u00i = -ct * sp;
    const float u01r = -st * cm, u01i = -st * sm;
    const float u10r =  st * cm, u10i = -st * sm;
    const float u11r =  ct * cp, u11i =  ct * sp;
    float* o = gt + i * kGateF;
    if (d == 1 && w >= 6) {
        // h = g^dag Z g: h00 = |u00|^2-|u10|^2, h01 = conj(u00)u01 - conj(u10)u11
        o[0] = (u00r * u00r + u00i * u00i) - (u10r * u10r + u10i * u10i);
        o[1] = (u00r * u01r + u00i * u01i) - (u10r * u11r + u10i * u11i);
        o[2] = (u00r * u01i - u00i * u01r) - (u10r * u11i - u10i * u11r);
        o[3] = 0.0f; o[4] = 0.0f; o[5] = 0.0f; o[6] = 0.0f; o[7] = 0.0f;
    } else {
        o[0] = u00r;  o[1] = u00i;
        o[2] = u01r;  o[3] = u01i;
        o[4] = u10r;  o[5] = u10i;
        o[6] = u11r;  o[7] = u11i;
    }
}

// ---------------- fast sincos (half-angle folded into revolution scale) ----------------
// v_sin/v_cos take REVOLUTIONS; our angles give |rev| < 0.5 (inputs) / < 0.08
// (expvals), far inside the +-256 valid range -> skip libm range reduction.
__device__ __forceinline__ void fastsc(float a, float& s, float& c) {
#if __has_builtin(__builtin_amdgcn_sinf) && __has_builtin(__builtin_amdgcn_cosf)
    const float r = a * 0.07957747154594767f;   // 0.5 / (2*pi)
    s = __builtin_amdgcn_sinf(r);
    c = __builtin_amdgcn_cosf(r);
#else
    __sincosf(0.5f * a, &s, &c);
#endif
}

// ---------------- shuffle backends ----------------
template <int CTRL>
__device__ __forceinline__ float f_dpp(float x) {
    return __builtin_bit_cast(float, __builtin_amdgcn_update_dpp(
        0, __builtin_bit_cast(int, x), CTRL, 0xF, 0xF, true));
}
constexpr int kDppXor1 = 0xB1;   // quad_perm [1,0,3,2]  = lane^1
constexpr int kDppXor2 = 0x4E;   // quad_perm [2,3,0,1]  = lane^2
constexpr int kDppXor8 = 0x128;  // row_ror:8 (16-lane row) = lane^8  [validated r7/r8]

// partner fetch at lane distance 1<<MODE: 0,1,3 via DPP (VALU); 2,4,5 via shfl (DS).
// permlane16/32_swap is BANNED: 3 failed rounds (r3, r6, r10).
template <int MODE>
__device__ __forceinline__ float lane_partner(float x) {
    if constexpr (MODE == 0) return f_dpp<kDppXor1>(x);
    else if constexpr (MODE == 1) return f_dpp<kDppXor2>(x);
    else if constexpr (MODE == 3) return f_dpp<kDppXor8>(x);
    else if constexpr (MODE == 2) return __shfl_xor(x, 4, 64);
    else if constexpr (MODE == 4) return __shfl_xor(x, 16, 64);
    else return __shfl_xor(x, 32, 64);
}
template <int MODE>
__device__ __forceinline__ v2f partner2(v2f v) {
    v2f r;
    r.x = lane_partner<MODE>(v.x);
    r.y = lane_partner<MODE>(v.y);
    return r;
}

__device__ __forceinline__ v2f sel2(int c, v2f a, v2f b) { return c ? a : b; }

// ---------------- gate helper (2 packed samples, 4 amps/lane) ----------------
// amp index k = (lane<<2)|reg; wire w -> index bit 7-w.
// wires 0..5 -> lane bits 5..0; wires 6,7 -> reg bits 1,0 (folded as Hermitian forms).
template <int MODE>
__device__ __forceinline__ void gate_p(v2f (&re)[4], v2f (&im)[4], int bit,
                                       const float* __restrict__ gp) {
    const float aR = bit ? gp[6] : gp[0];
    const float aI = bit ? gp[7] : gp[1];
    const float bR = bit ? gp[4] : gp[2];
    const float bI = bit ? gp[5] : gp[3];
#pragma unroll
    for (int r = 0; r < 4; ++r) {
        const v2f pre = partner2<MODE>(re[r]);
        const v2f pim = partner2<MODE>(im[r]);
        const v2f mre = re[r], mim = im[r];
        re[r] = aR * mre - aI * mim + bR * pre - bI * pim;   // v_pk_fma_f32 chain
        im[r] = aR * mim + aI * mre + bR * pim + bI * pre;
    }
}

// ---------------- one circuit sim: 2 packed samples, 3 Walsh streams out ----------------
// State after AngleEmbedding + depth-0 Rot + CNOT-ring1 built directly as a permuted
// spinor product (coefficients loaded wave-uniform, values selected by cndmask —
// NEVER select the address: per-lane gate loads caused the r13 regression);
// depth-1 Rot gates on lane-bit wires; reg-bit wires (6,7) folded as Hermitian
// quadratic forms; CNOT-ring2 folded into Walsh parities of the reduction.
__device__ __forceinline__ void sim2p(const float (&ang)[2][8],
                                      const float* __restrict__ g0,
                                      const float* __restrict__ g1,
                                      int lane, const v2f (&sv)[6],
                                      v2f& WPo, v2f& WR1o, v2f& WR0o) {
    const int l0 = lane & 1,        l1 = (lane >> 1) & 1, l2 = (lane >> 2) & 1;
    const int l3 = (lane >> 3) & 1, l4 = (lane >> 4) & 1, l5 = (lane >> 5) & 1;

    v2f re[4], im[4];
    {
        // per-wire spinor after RY(ang) then d0 Rot, packed over samples
        v2f spr[8][2], spi[8][2];
#pragma unroll
        for (int w = 0; w < 8; ++w) {
            float s0, c0, s1, c1;
            fastsc(ang[0][w], s0, c0);
            fastsc(ang[1][w], s1, c1);
            const v2f cs = {c0, c1}, sn = {s0, s1};
            const float* gp = g0 + w * kGateF;
            spr[w][0] = gp[0] * cs + gp[2] * sn;
            spi[w][0] = gp[1] * cs + gp[3] * sn;
            spr[w][1] = gp[4] * cs + gp[6] * sn;
            spi[w][1] = gp[5] * cs + gp[7] * sn;
        }
        // ring1 inverse bit map (x = pre-ring1 wire bits; (lane,reg) = post-ring1):
        //  x0=l5^r0  x1=l5^l4^r0  x2=l4^l3  x3=l3^l2  x4=l2^l1  x5=l1^l0
        //  x6=l0^r1  x7=r1^r0
        const int x2 = l4 ^ l3, x3 = l3 ^ l2, x4 = l2 ^ l1, x5 = l1 ^ l0;
        v2f t1r, t1i, t2r, t2i;
        {
            const v2f ar = sel2(x2, spr[2][1], spr[2][0]), ai = sel2(x2, spi[2][1], spi[2][0]);
            const v2f br = sel2(x3, spr[3][1], spr[3][0]), bi = sel2(x3, spi[3][1], spi[3][0]);
            t1r = ar * br - ai * bi; t1i = ar * bi + ai * br;
        }
        {
            const v2f ar = sel2(x4, spr[4][1], spr[4][0]), ai = sel2(x4, spi[4][1], spi[4][0]);
            const v2f br = sel2(x5, spr[5][1], spr[5][0]), bi = sel2(x5, spi[5][1], spi[5][0]);
            t2r = ar * br - ai * bi; t2i = ar * bi + ai * br;
        }
        const v2f Lr = t1r * t2r - t1i * t2i, Li = t1r * t2i + t1i * t2r;
        // Q(r0) = s0[l5^r0] * s1[l5^l4^r0]
        const int xa = l5, xb = l5 ^ l4;
        const v2f a0r = sel2(xa, spr[0][1], spr[0][0]), a0i = sel2(xa, spi[0][1], spi[0][0]);
        const v2f a1r = sel2(xa, spr[0][0], spr[0][1]), a1i = sel2(xa, spi[0][0], spi[0][1]);
        const v2f b0r = sel2(xb, spr[1][1], spr[1][0]), b0i = sel2(xb, spi[1][1], spi[1][0]);
        const v2f b1r = sel2(xb, spr[1][0], spr[1][1]), b1i = sel2(xb, spi[1][0], spi[1][1]);
        const v2f Q0r = a0r * b0r - a0i * b0i, Q0i = a0r * b0i + a0i * b0r;
        const v2f Q1r = a1r * b1r - a1i * b1i, Q1i = a1r * b1i + a1i * b1r;
        // R(r1) = s6[l0^r1]; S(r0,r1) = s7[r1^r0]
        const v2f R0r = sel2(l0, spr[6][1], spr[6][0]), R0i = sel2(l0, spi[6][1], spi[6][0]);
        const v2f R1r = sel2(l0, spr[6][0], spr[6][1]), R1i = sel2(l0, spi[6][0], spi[6][1]);
        const v2f S0r = spr[7][0], S0i = spi[7][0];
        const v2f S1r = spr[7][1], S1i = spi[7][1];
        v2f RSr[4], RSi[4];
        RSr[0] = R0r * S0r - R0i * S0i; RSi[0] = R0r * S0i + R0i * S0r;  // r=0
        RSr[1] = R0r * S1r - R0i * S1i; RSi[1] = R0r * S1i + R0i * S1r;  // r=1
        RSr[2] = R1r * S1r - R1i * S1i; RSi[2] = R1r * S1i + R1i * S1r;  // r=2
        RSr[3] = R1r * S0r - R1i * S0i; RSi[3] = R1r * S0i + R1i * S0r;  // r=3
        const v2f LQ0r = Lr * Q0r - Li * Q0i, LQ0i = Lr * Q0i + Li * Q0r;
        const v2f LQ1r = Lr * Q1r - Li * Q1i, LQ1i = Lr * Q1i + Li * Q1r;
        re[0] = LQ0r * RSr[0] - LQ0i * RSi[0]; im[0] = LQ0r * RSi[0] + LQ0i * RSr[0];
        re[1] = LQ1r * RSr[1] - LQ1i * RSi[1]; im[1] = LQ1r * RSi[1] + LQ1i * RSr[1];
        re[2] = LQ0r * RSr[2] - LQ0i * RSi[2]; im[2] = LQ0r * RSi[2] + LQ0i * RSr[2];
        re[3] = LQ1r * RSr[3] - LQ1i * RSi[3]; im[3] = LQ1r * RSi[3] + LQ1i * RSr[3];
    }

    // --- depth-1 Rot gates on lane-bit wires (wire w on lane bit 5-w) ---
    gate_p<5>(re, im, l5, g1 + 0 * kGateF);     // wire0: xor32 (shfl)
    gate_p<4>(re, im, l4, g1 + 1 * kGateF);     // wire1: xor16 (shfl)
    gate_p<3>(re, im, l3, g1 + 2 * kGateF);     // wire2: xor8 (DPP row_ror:8)
    gate_p<2>(re, im, l2, g1 + 3 * kGateF);     // wire3: xor4 (shfl)
    gate_p<1>(re, im, l1, g1 + 4 * kGateF);     // wire4: xor2 (DPP)
    gate_p<0>(re, im, l0, g1 + 5 * kGateF);     // wire5: xor1 (DPP)

    // --- reg-bit wires via Hermitian forms (packed) ---
    const v2f p0 = re[0] * re[0] + im[0] * im[0];
    const v2f p1 = re[1] * re[1] + im[1] * im[1];
    const v2f p2 = re[2] * re[2] + im[2] * im[2];
    const v2f p3 = re[3] * re[3] + im[3] * im[3];
    v2f P = (p0 + p1) + (p2 + p3);
    const float* h6 = g1 + 6 * kGateF;
    const float* h7 = g1 + 7 * kGateF;
    const v2f z1r = re[0] * re[2] + im[0] * im[2] + re[1] * re[3] + im[1] * im[3];
    const v2f z1i = re[0] * im[2] - im[0] * re[2] + re[1] * im[3] - im[1] * re[3];
    v2f R1 = h6[0] * ((p0 + p1) - (p2 + p3)) + 2.0f * (h6[1] * z1r - h6[2] * z1i);
    const v2f z0r = re[0] * re[1] + im[0] * im[1] + re[2] * re[3] + im[2] * im[3];
    const v2f z0i = re[0] * im[1] - im[0] * re[1] + re[2] * im[3] - im[2] * re[3];
    v2f R0 = h7[0] * ((p0 - p1) + (p2 - p3)) + 2.0f * (h7[1] * z0r - h7[2] * z0i);

    // --- ring2 folded into Walsh parities: full WHT butterfly, W[m] at lane m ---
    // per level: v' = partner + sv[q] * v  (sv = packed ±1 from lane bit q)
#pragma unroll
    for (int st = 0; st < 3; ++st) {
        v2f v = (st == 0) ? P : (st == 1) ? R1 : R0;
        v2f d;
        d = partner2<0>(v); v = d + sv[0] * v;
        d = partner2<1>(v); v = d + sv[1] * v;
        d = partner2<2>(v); v = d + sv[2] * v;
        d = partner2<3>(v); v = d + sv[3] * v;
        d = partner2<4>(v); v = d + sv[4] * v;
        d = partner2<5>(v); v = d + sv[5] * v;
        if (st == 0) P = v; else if (st == 1) R1 = v; else R0 = v;
    }
    WPo = P; WR1o = R1; WR0o = R0;
}

// scatter the 8 expvals (E_w = Walsh coeffs at fixed lanes), element stride STRIDE
// masks: E0:R1@10  E1:R0@5  E2:P@40  E3:P@20  E4:P@42  E5:P@21  E6:R1@42  E7:R0@21
template <int STRIDE, typename PT>
__device__ __forceinline__ void scatter_ev(PT e, int lane, float P, float R1, float R0) {
    if (lane == 10) e[0 * STRIDE] = R1;
    if (lane ==  5) e[1 * STRIDE] = R0;
    if (lane == 40) e[2 * STRIDE] = P;
    if (lane == 20) e[3 * STRIDE] = P;
    if (lane == 42) { e[4 * STRIDE] = P; e[6 * STRIDE] = R1; }
    if (lane == 21) { e[5 * STRIDE] = P; e[7 * STRIDE] = R0; }
}

// ---------------- fused both-layer kernel ----------------
// block = 512 threads = 8 waves = the 8 circuits of one (t, sample-pair);
// 2 packed samples per wave; layer-0 results exchanged through 512 B of LDS.
// exch layout [sample][wire][block]: phase-1 angle gather = 2x float4 broadcast reads.
__global__ __launch_bounds__(512, 4) void fused_kernel(const float* __restrict__ x,
                                                       const float* __restrict__ gt,
                                                       float* __restrict__ out) {
    const int widx = __builtin_amdgcn_readfirstlane(threadIdx.x >> 6);  // circuit u
    const int lane = threadIdx.x & 63;
    const int tt = blockIdx.x >> 7;          // timestep
    const int b0 = (blockIdx.x & 127) << 1;  // first sample of pair

    __shared__ float exch[2][8][8];          // [sample][wire][block]

    v2f sv[6];
#pragma unroll
    for (int q = 0; q < 6; ++q) {
        const float s = ((lane >> q) & 1) ? -1.0f : 1.0f;
        sv[q].x = s; sv[q].y = s;
    }

    const int c = tt * kNB + widx;
    v2f WP, WR1, WR0;
    float ang[2][8];

    // ---- phase 0: layer-0 circuit (t, widx), samples b0, b0+1 ----
    {
        const float* g0 = gt + (size_t)c * kGates * kGateF;
        const float* g1 = g0 + 8 * kGateF;
#pragma unroll
        for (int s = 0; s < 2; ++s) {
            const float* ab = x + (((b0 + s) * kT + tt) * kD + widx * kNQ);
#pragma unroll
            for (int w = 0; w < 8; ++w) ang[s][w] = ab[w];
        }
        sim2p(ang, g0, g1, lane, sv, WP, WR1, WR0);
        scatter_ev<8>(&exch[0][0][widx], lane, WP.x, WR1.x, WR0.x);
        scatter_ev<8>(&exch[1][0][widx], lane, WP.y, WR1.y, WR0.y);
    }
    __syncthreads();
    // ---- phase 1: layer-1 circuit (t, widx) gathers feature widx of every block ----
    {
        const float* g0 = gt + (size_t)(kCirc + c) * kGates * kGateF;
        const float* g1 = g0 + 8 * kGateF;
#pragma unroll
        for (int s = 0; s < 2; ++s) {
            const float4 v0 = *reinterpret_cast<const float4*>(&exch[s][widx][0]);
            const float4 v1 = *reinterpret_cast<const float4*>(&exch[s][widx][4]);
            ang[s][0] = v0.x; ang[s][1] = v0.y; ang[s][2] = v0.z; ang[s][3] = v0.w;
            ang[s][4] = v1.x; ang[s][5] = v1.y; ang[s][6] = v1.z; ang[s][7] = v1.w;
        }
        sim2p(ang, g0, g1, lane, sv, WP, WR1, WR0);
        scatter_ev<1>(out + (((b0 + 0) * kT + tt) * kD + widx * kNQ), lane, WP.x, WR1.x, WR0.x);
        scatter_ev<1>(out + (((b0 + 1) * kT + tt) * kD + widx * kNQ), lane, WP.y, WR1.y, WR0.y);
    }
}

}  // namespace

extern "C" void kernel_launch(void* const* d_in, const int* in_sizes, int n_in,
                              void* d_out, int out_size, void* d_ws, size_t ws_size,
                              hipStream_t stream) {
    const float* x     = (const float*)d_in[0];   // (B, T, D) fp32
    const float* theta = (const float*)d_in[1];   // (T, NL, NB, DEPTH, NQ, 3) fp32
    float* out = (float*)d_out;                   // (B, T, D) fp32

    float* gt = (float*)d_ws;                     // gate table: 2*64*16*8 floats (64 KB)

    precompute_gates<<<(kNL * kCirc * kGates + 255) / 256, 256, 0, stream>>>(theta, gt);
    // 8 timesteps x 128 sample-pairs; 512 threads = 8 circuits x 2 packed samples/wave
    fused_kernel<<<kT * (kB / 2), 512, 0, stream>>>(x, gt, out);
}

// Round 15
// 30.422 us; speedup vs baseline: 1.8676x; 1.1545x over previous
//
#include <hip/hip_runtime.h>

namespace {

constexpr int kT   = 8;    // timesteps
constexpr int kB   = 256;  // batch
constexpr int kNQ  = 8;    // qubits per circuit
constexpr int kNB  = 8;    // blocks
constexpr int kD   = 64;   // features
constexpr int kNL  = 2;    // quantum layers
constexpr int kCirc = kT * kNB;        // 64 circuits per layer
constexpr int kGates = 2 * kNQ;        // 16 gate slots per circuit
constexpr int kGateF = 8;

// Walsh parity masks (validated r4-r14): wire-set of output w, bit j = wire j.
// g0={2,4,6} g1={3,5,7} g2={0,2} g3={1,3} g4={0,2,4} g5={1,3,5} g6={0,2,4,6} g7={1,3,5,7}
constexpr unsigned long long kMaskPacked =
    (0x54ULL << 0) | (0xA8ULL << 8) | (0x05ULL << 16) | (0x0AULL << 24) |
    (0x15ULL << 32) | (0x2AULL << 40) | (0x55ULL << 48) | (0xAAULL << 56);

// ---------------- gate precompute ----------------
// d=0 slots (w=0..7): full 2x2 complex Rot gate (8 floats)
// d=1 slots (w=0..7): Hermitian h = g^dag Z g as (alpha, Re h01, Im h01) [traceless]
__global__ void precompute_gates(const float* __restrict__ theta, float* __restrict__ gt) {
    int i = blockIdx.x * blockDim.x + threadIdx.x;
    if (i >= kNL * kCirc * kGates) return;
    int g = i & 15;
    int c = (i >> 4) & 63;
    int l = i >> 10;
    int t = c >> 3, u = c & 7;
    int d = g >> 3, w = g & 7;
    const float* th = theta + ((((t * kNL + l) * kNB + u) * 2 + d) * kNQ + w) * 3;
    float phi = th[0], tht = th[1], omg = th[2];
    float st, ct, sp, cp, sm, cm;
    __sincosf(0.5f * tht, &st, &ct);
    __sincosf(0.5f * (phi + omg), &sp, &cp);
    __sincosf(0.5f * (phi - omg), &sm, &cm);
    const float u00r =  ct * cp, u00i = -ct * sp;
    const float u01r = -st * cm, u01i = -st * sm;
    const float u10r =  st * cm, u10i = -st * sm;
    const float u11r =  ct * cp, u11i =  ct * sp;
    float* o = gt + i * kGateF;
    if (d == 1) {
        // h = g^dag Z g (Hermitian, traceless): h00 = |u00|^2-|u10|^2 = -h11,
        // h01 = conj(u00)u01 - conj(u10)u11
        o[0] = (u00r * u00r + u00i * u00i) - (u10r * u10r + u10i * u10i);
        o[1] = (u00r * u01r + u00i * u01i) - (u10r * u11r + u10i * u11i);
        o[2] = (u00r * u01i - u00i * u01r) - (u10r * u11i - u10i * u11r);
        o[3] = 0.0f; o[4] = 0.0f; o[5] = 0.0f; o[6] = 0.0f; o[7] = 0.0f;
    } else {
        o[0] = u00r;  o[1] = u00i;
        o[2] = u01r;  o[3] = u01i;
        o[4] = u10r;  o[5] = u10i;
        o[6] = u11r;  o[7] = u11i;
    }
}

// ---------------- fast sincos of a/2 ----------------
// v_sin/v_cos take REVOLUTIONS; |a/2/(2pi)| < 0.5 here -> no range reduction needed.
__device__ __forceinline__ void fastsc(float a, float& s, float& c) {
#if __has_builtin(__builtin_amdgcn_sinf) && __has_builtin(__builtin_amdgcn_cosf)
    const float r = a * 0.07957747154594767f;   // 0.5 / (2*pi)
    s = __builtin_amdgcn_sinf(r);
    c = __builtin_amdgcn_cosf(r);
#else
    __sincosf(0.5f * a, &s, &c);
#endif
}

// B_j entry select: h_j if wire j in mask, else identity.
// B = [[b00, (b01r,-?)],...]: b00 real, B[0][1] = (b01r,b01i), B[1][0] = conj, b11 real.
__device__ __forceinline__ void bsel(const float* __restrict__ hh, int j, unsigned mask,
                                     float& b00, float& b01r, float& b01i, float& b11) {
    const float* hp = hh + j * kGateF;
    const bool m = (mask >> j) & 1u;
    const float a = hp[0], hr = hp[1], hi = hp[2];
    b00  = m ? a   : 1.0f;
    b01r = m ? hr  : 0.0f;
    b01i = m ? hi  : 0.0f;
    b11  = m ? -a  : 1.0f;
}

// ---------------- one circuit sim via 16-state transfer-matrix DP ----------------
// E_w = sum_{b,b'} prod_j rho_j[b_j,b'_j] * prod_j B_j[l'_j, l_j]
// with l = ring1(b): l_j = b_0^..^b_j (j>=1), l_0 = total^b_0.
// State: (p,p') prefix pair + (b0,b'0) kept for the l_0 wrap; 16 complex.
// rho_j = sigma_j sigma_j^dag, sigma_j = Rot0_j * RY(ang_j)|0>.
__device__ __forceinline__ float simdp(const float (&ang)[8],
                                       const float* __restrict__ g0,   // d0 gates
                                       const float* __restrict__ hh,   // d1 hermitians
                                       unsigned mask) {
    // per-wire density-matrix entries: rho[0][0]=r00, rho[1][1]=r11 (real),
    // rho[0][1] = (r01r, r01i), rho[1][0] = conj
    float r00[8], r11[8], r01r[8], r01i[8];
#pragma unroll
    for (int j = 0; j < 8; ++j) {
        float sn, cs;
        fastsc(ang[j], sn, cs);
        const float* gp = g0 + j * kGateF;
        const float s0r = gp[0] * cs + gp[2] * sn, s0i = gp[1] * cs + gp[3] * sn;
        const float s1r = gp[4] * cs + gp[6] * sn, s1i = gp[5] * cs + gp[7] * sn;
        r00[j]  = s0r * s0r + s0i * s0i;
        r11[j]  = s1r * s1r + s1i * s1i;
        r01r[j] = s0r * s1r + s0i * s1i;   // sigma0 * conj(sigma1)
        r01i[j] = s0i * s1r - s0r * s1i;
    }

    // rho_j[a][ap] fetch (all indices compile-time in unrolled loops)
#define RHO(j, a, ap, rr, ri)                                        \
    do {                                                             \
        if ((a) == (ap)) { rr = (a) ? r11[j] : r00[j]; ri = 0.0f; }  \
        else if ((a) == 0) { rr = r01r[j]; ri = r01i[j]; }           \
        else { rr = r01r[j]; ri = -r01i[j]; }                        \
    } while (0)

    float Vr[4][2][2], Vi[4][2][2];   // [b0*2+b'0][p][p']

    // init fused with step j=1: V = rho0[b0,b'0] * rho1[p^b0, p'^b'0] * B1[p'][p]
    {
        float b00, b01r, b01i, b11;
        bsel(hh, 1, mask, b00, b01r, b01i, b11);
#pragma unroll
        for (int b0 = 0; b0 < 2; ++b0)
#pragma unroll
        for (int bp = 0; bp < 2; ++bp) {
            float q0r, q0i;
            RHO(0, b0, bp, q0r, q0i);
#pragma unroll
            for (int p = 0; p < 2; ++p)
#pragma unroll
            for (int pp = 0; pp < 2; ++pp) {
                float q1r, q1i;
                RHO(1, p ^ b0, pp ^ bp, q1r, q1i);
                const float tr = q0r * q1r - q0i * q1i;
                const float ti = q0r * q1i + q0i * q1r;
                float Br, Bi;
                if (p == pp) { Br = p ? b11 : b00; Bi = 0.0f; }
                else if (pp == 0) { Br = b01r; Bi = b01i; }      // B[0][1]
                else { Br = b01r; Bi = -b01i; }                  // B[1][0] = conj
                Vr[b0 * 2 + bp][p][pp] = tr * Br - ti * Bi;
                Vi[b0 * 2 + bp][p][pp] = tr * Bi + ti * Br;
            }
        }
    }

    // steps j = 2..7: V'[p,p'] = B_j[p'][p] * sum_{q,q'} rho_j[p^q, p'^q'] V[q,q']
#pragma unroll
    for (int j = 2; j < 8; ++j) {
        float b00, b01r, b01i, b11;
        bsel(hh, j, mask, b00, b01r, b01i, b11);
        const float c00 = r00[j], c11 = r11[j], c01r = r01r[j], c01i = r01i[j];
#pragma unroll
        for (int bb = 0; bb < 4; ++bb) {
            float nr[2][2], ni[2][2];
#pragma unroll
            for (int p = 0; p < 2; ++p)
#pragma unroll
            for (int pp = 0; pp < 2; ++pp) {
                // q=p,q'=pp: rho[0][0]; q=p,q'=pp^1: rho[0][1];
                // q=p^1,q'=pp: rho[1][0]=conj; q=p^1,q'=pp^1: rho[1][1]
                float sr = c00 * Vr[bb][p][pp] + c11 * Vr[bb][p ^ 1][pp ^ 1];
                float si = c00 * Vi[bb][p][pp] + c11 * Vi[bb][p ^ 1][pp ^ 1];
                sr += c01r * Vr[bb][p][pp ^ 1] - c01i * Vi[bb][p][pp ^ 1];
                si += c01r * Vi[bb][p][pp ^ 1] + c01i * Vr[bb][p][pp ^ 1];
                sr += c01r * Vr[bb][p ^ 1][pp] + c01i * Vi[bb][p ^ 1][pp];
                si += c01r * Vi[bb][p ^ 1][pp] - c01i * Vr[bb][p ^ 1][pp];
                float Br, Bi;
                if (p == pp) { Br = p ? b11 : b00; Bi = 0.0f; }
                else if (pp == 0) { Br = b01r; Bi = b01i; }
                else { Br = b01r; Bi = -b01i; }
                nr[p][pp] = sr * Br - si * Bi;
                ni[p][pp] = sr * Bi + si * Br;
            }
            Vr[bb][0][0] = nr[0][0]; Vi[bb][0][0] = ni[0][0];
            Vr[bb][0][1] = nr[0][1]; Vi[bb][0][1] = ni[0][1];
            Vr[bb][1][0] = nr[1][0]; Vi[bb][1][0] = ni[1][0];
            Vr[bb][1][1] = nr[1][1]; Vi[bb][1][1] = ni[1][1];
        }
    }

    // final: E = Re sum V[(b0,b'0)][p][p'] * B0[p'^b'0][p^b0]   (l_0 wrap)
    float E = 0.0f;
    {
        float b00, b01r, b01i, b11;
        bsel(hh, 0, mask, b00, b01r, b01i, b11);
#pragma unroll
        for (int b0 = 0; b0 < 2; ++b0)
#pragma unroll
        for (int bp = 0; bp < 2; ++bp)
#pragma unroll
        for (int p = 0; p < 2; ++p)
#pragma unroll
        for (int pp = 0; pp < 2; ++pp) {
            const int cc = p ^ b0;    // l_0 (ket)
            const int rr = pp ^ bp;   // l'_0 (bra)
            float Br, Bi;
            if (rr == cc) { Br = cc ? b11 : b00; Bi = 0.0f; }
            else if (rr == 0) { Br = b01r; Bi = b01i; }
            else { Br = b01r; Bi = -b01i; }
            E += Vr[b0 * 2 + bp][p][pp] * Br - Vi[b0 * 2 + bp][p][pp] * Bi;
        }
    }
#undef RHO
    return E;
}

// ---------------- fused both-layer kernel ----------------
// wave = (t, sample b); lane = (u:3, w:3) computes expval w of circuit u.
// Phase 0 (layer 0) -> in-wave shfl redistribution -> phase 1 (layer 1).
// No LDS, no barriers, no per-gate shuffles.
__global__ __launch_bounds__(256) void fused_kernel(const float* __restrict__ x,
                                                    const float* __restrict__ gt,
                                                    float* __restrict__ out) {
    const int wid  = blockIdx.x * 4 + (threadIdx.x >> 6);  // global wave id
    const int lane = threadIdx.x & 63;
    const int tt = wid >> 8;          // timestep
    const int b  = wid & 255;         // sample
    const int u  = lane >> 3;         // circuit within timestep
    const int w  = lane & 7;          // output wire
    const unsigned mask = (unsigned)((kMaskPacked >> (w * 8)) & 0xFF);

    // ---- phase 0: layer-0 circuit (t,u), angles from x ----
    float ang[8];
    {
        const float* ab = x + ((b * kT + tt) * kD + u * kNQ);
#pragma unroll
        for (int j = 0; j < 8; ++j) ang[j] = ab[j];
    }
    const float* base0 = gt + (size_t)(tt * kNB + u) * kGates * kGateF;
    float E = simdp(ang, base0, base0 + 8 * kGateF, mask);

    // ---- redistribute: layer-1 circuit u needs H0[t,b,i*8+u] = lane i*8+u ----
#pragma unroll
    for (int i = 0; i < 8; ++i) ang[i] = __shfl(E, i * 8 + u, 64);

    // ---- phase 1: layer-1 circuit (t,u) ----
    const float* base1 = gt + (size_t)(kCirc + tt * kNB + u) * kGates * kGateF;
    E = simdp(ang, base1, base1 + 8 * kGateF, mask);

    out[(b * kT + tt) * kD + u * kNQ + w] = E;   // coalesced: 64 consecutive floats/wave
}

}  // namespace

extern "C" void kernel_launch(void* const* d_in, const int* in_sizes, int n_in,
                              void* d_out, int out_size, void* d_ws, size_t ws_size,
                              hipStream_t stream) {
    const float* x     = (const float*)d_in[0];   // (B, T, D) fp32
    const float* theta = (const float*)d_in[1];   // (T, NL, NB, DEPTH, NQ, 3) fp32
    float* out = (float*)d_out;                   // (B, T, D) fp32

    float* gt = (float*)d_ws;                     // gate table: 2*64*16*8 floats (64 KB)

    precompute_gates<<<(kNL * kCirc * kGates + 255) / 256, 256, 0, stream>>>(theta, gt);
    // 8 timesteps x 256 samples = 2048 waves; 256 threads = 4 waves/block
    fused_kernel<<<kT * kB / 4, 256, 0, stream>>>(x, gt, out);
}

// Round 16
// 24.945 us; speedup vs baseline: 2.2776x; 1.2195x over previous
//
#include <hip/hip_runtime.h>

namespace {

constexpr int kT   = 8;    // timesteps
constexpr int kB   = 256;  // batch
constexpr int kNQ  = 8;    // qubits per circuit
constexpr int kNB  = 8;    // blocks
constexpr int kD   = 64;   // features
constexpr int kNL  = 2;    // quantum layers
constexpr int kGateF = 8;
constexpr int kCircStride = 16 * kGateF + 4;   // 132: pad so u-strides hit distinct banks

// Walsh parity masks (validated r4-r15): wire-set of output w, bit j = wire j.
// g0={2,4,6} g1={3,5,7} g2={0,2} g3={1,3} g4={0,2,4} g5={1,3,5} g6={0,2,4,6} g7={1,3,5,7}
constexpr unsigned long long kMaskPacked =
    (0x54ULL << 0) | (0xA8ULL << 8) | (0x05ULL << 16) | (0x0AULL << 24) |
    (0x15ULL << 32) | (0x2AULL << 40) | (0x55ULL << 48) | (0xAAULL << 56);

// ---------------- fast sincos of a/2 ----------------
// v_sin/v_cos take REVOLUTIONS; |a| small here (inputs ~N(0,1), expvals in [-1,1],
// thetas ~0.01) -> |rev| << 0.5, no range reduction needed.
__device__ __forceinline__ void fastsc(float a, float& s, float& c) {
#if __has_builtin(__builtin_amdgcn_sinf) && __has_builtin(__builtin_amdgcn_cosf)
    const float r = a * 0.07957747154594767f;   // 0.5 / (2*pi)
    s = __builtin_amdgcn_sinf(r);
    c = __builtin_amdgcn_cosf(r);
#else
    __sincosf(0.5f * a, &s, &c);
#endif
}

// B_j entry select: h_j if wire j in mask, else identity.
__device__ __forceinline__ void bsel(const float* __restrict__ hh, int j, unsigned mask,
                                     float& b00, float& b01r, float& b01i, float& b11) {
    const float* hp = hh + j * kGateF;
    const bool m = (mask >> j) & 1u;
    const float a = hp[0], hr = hp[1], hi = hp[2];
    b00  = m ? a   : 1.0f;
    b01r = m ? hr  : 0.0f;
    b01i = m ? hi  : 0.0f;
    b11  = m ? -a  : 1.0f;
}

// ---------------- one circuit sim via 16-state transfer-matrix DP ----------------
// E_w = sum_{b,b'} prod_j rho_j[b_j,b'_j] * prod_j B_j[l'_j, l_j]
// with l = ring1(b): l_j = b_0^..^b_j (j>=1), l_0 = total^b_0.
// State: (p,p') prefix pair + (b0,b'0) kept for the l_0 wrap; 16 complex.
// rho_j = sigma_j sigma_j^dag, sigma_j = Rot0_j * RY(ang_j)|0>.  [validated r15]
__device__ __forceinline__ float simdp(const float (&ang)[8],
                                       const float* __restrict__ g0,   // d0 gates (LDS)
                                       const float* __restrict__ hh,   // d1 hermitians (LDS)
                                       unsigned mask) {
    float r00[8], r11[8], r01r[8], r01i[8];
#pragma unroll
    for (int j = 0; j < 8; ++j) {
        float sn, cs;
        fastsc(ang[j], sn, cs);
        const float* gp = g0 + j * kGateF;
        const float s0r = gp[0] * cs + gp[2] * sn, s0i = gp[1] * cs + gp[3] * sn;
        const float s1r = gp[4] * cs + gp[6] * sn, s1i = gp[5] * cs + gp[7] * sn;
        r00[j]  = s0r * s0r + s0i * s0i;
        r11[j]  = s1r * s1r + s1i * s1i;
        r01r[j] = s0r * s1r + s0i * s1i;   // sigma0 * conj(sigma1)
        r01i[j] = s0i * s1r - s0r * s1i;
    }

#define RHO(j, a, ap, rr, ri)                                        \
    do {                                                             \
        if ((a) == (ap)) { rr = (a) ? r11[j] : r00[j]; ri = 0.0f; }  \
        else if ((a) == 0) { rr = r01r[j]; ri = r01i[j]; }           \
        else { rr = r01r[j]; ri = -r01i[j]; }                        \
    } while (0)

    float Vr[4][2][2], Vi[4][2][2];   // [b0*2+b'0][p][p']

    // init fused with step j=1: V = rho0[b0,b'0] * rho1[p^b0, p'^b'0] * B1[p'][p]
    {
        float b00, b01r, b01i, b11;
        bsel(hh, 1, mask, b00, b01r, b01i, b11);
#pragma unroll
        for (int b0 = 0; b0 < 2; ++b0)
#pragma unroll
        for (int bp = 0; bp < 2; ++bp) {
            float q0r, q0i;
            RHO(0, b0, bp, q0r, q0i);
#pragma unroll
            for (int p = 0; p < 2; ++p)
#pragma unroll
            for (int pp = 0; pp < 2; ++pp) {
                float q1r, q1i;
                RHO(1, p ^ b0, pp ^ bp, q1r, q1i);
                const float tr = q0r * q1r - q0i * q1i;
                const float ti = q0r * q1i + q0i * q1r;
                float Br, Bi;
                if (p == pp) { Br = p ? b11 : b00; Bi = 0.0f; }
                else if (pp == 0) { Br = b01r; Bi = b01i; }      // B[0][1]
                else { Br = b01r; Bi = -b01i; }                  // B[1][0] = conj
                Vr[b0 * 2 + bp][p][pp] = tr * Br - ti * Bi;
                Vi[b0 * 2 + bp][p][pp] = tr * Bi + ti * Br;
            }
        }
    }

    // steps j = 2..7: V'[p,p'] = B_j[p'][p] * sum_{q,q'} rho_j[p^q, p'^q'] V[q,q']
#pragma unroll
    for (int j = 2; j < 8; ++j) {
        float b00, b01r, b01i, b11;
        bsel(hh, j, mask, b00, b01r, b01i, b11);
        const float c00 = r00[j], c11 = r11[j], c01r = r01r[j], c01i = r01i[j];
#pragma unroll
        for (int bb = 0; bb < 4; ++bb) {
            float nr[2][2], ni[2][2];
#pragma unroll
            for (int p = 0; p < 2; ++p)
#pragma unroll
            for (int pp = 0; pp < 2; ++pp) {
                float sr = c00 * Vr[bb][p][pp] + c11 * Vr[bb][p ^ 1][pp ^ 1];
                float si = c00 * Vi[bb][p][pp] + c11 * Vi[bb][p ^ 1][pp ^ 1];
                sr += c01r * Vr[bb][p][pp ^ 1] - c01i * Vi[bb][p][pp ^ 1];
                si += c01r * Vi[bb][p][pp ^ 1] + c01i * Vr[bb][p][pp ^ 1];
                sr += c01r * Vr[bb][p ^ 1][pp] + c01i * Vi[bb][p ^ 1][pp];
                si += c01r * Vi[bb][p ^ 1][pp] - c01i * Vr[bb][p ^ 1][pp];
                float Br, Bi;
                if (p == pp) { Br = p ? b11 : b00; Bi = 0.0f; }
                else if (pp == 0) { Br = b01r; Bi = b01i; }
                else { Br = b01r; Bi = -b01i; }
                nr[p][pp] = sr * Br - si * Bi;
                ni[p][pp] = sr * Bi + si * Br;
            }
            Vr[bb][0][0] = nr[0][0]; Vi[bb][0][0] = ni[0][0];
            Vr[bb][0][1] = nr[0][1]; Vi[bb][0][1] = ni[0][1];
            Vr[bb][1][0] = nr[1][0]; Vi[bb][1][0] = ni[1][0];
            Vr[bb][1][1] = nr[1][1]; Vi[bb][1][1] = ni[1][1];
        }
    }

    // final: E = Re sum V[(b0,b'0)][p][p'] * B0[p'^b'0][p^b0]   (l_0 wrap)
    float E = 0.0f;
    {
        float b00, b01r, b01i, b11;
        bsel(hh, 0, mask, b00, b01r, b01i, b11);
#pragma unroll
        for (int b0 = 0; b0 < 2; ++b0)
#pragma unroll
        for (int bp = 0; bp < 2; ++bp)
#pragma unroll
        for (int p = 0; p < 2; ++p)
#pragma unroll
        for (int pp = 0; pp < 2; ++pp) {
            const int cc = p ^ b0;    // l_0 (ket)
            const int rr = pp ^ bp;   // l'_0 (bra)
            float Br, Bi;
            if (rr == cc) { Br = cc ? b11 : b00; Bi = 0.0f; }
            else if (rr == 0) { Br = b01r; Bi = b01i; }
            else { Br = b01r; Bi = -b01i; }
            E += Vr[b0 * 2 + bp][p][pp] * Br - Vi[b0 * 2 + bp][p][pp] * Bi;
        }
    }
#undef RHO
    return E;
}

// ---------------- single fused kernel: gate build (LDS) + both layers ----------------
// block = 256 threads = 4 waves, all sharing one timestep tt (256 wids/tt).
// Gate build: thread i computes ONE gate slot (l,u,d,w) into LDS (theta reads
// coalesced: slot order is linear in theta layout). One barrier. Then the DP:
// wave = (t, sample b); lane = (u:3, w:3) computes expval w of circuit u.
__global__ __launch_bounds__(256) void fused_kernel(const float* __restrict__ x,
                                                    const float* __restrict__ theta,
                                                    float* __restrict__ out) {
    __shared__ float gl[kNL * kNB * kCircStride];   // 2112 floats = 8448 B

    const int tid  = threadIdx.x;
    const int wid  = blockIdx.x * 4 + (tid >> 6);
    const int lane = tid & 63;
    const int tt = wid >> 8;          // timestep (block-uniform)
    const int b  = wid & 255;         // sample
    const int u  = lane >> 3;         // circuit within timestep
    const int w  = lane & 7;          // output wire
    const unsigned mask = (unsigned)((kMaskPacked >> (w * 8)) & 0xFF);

    // ---- gate build: one slot per thread ----
    {
        const int l  = tid >> 7;
        const int uu = (tid >> 4) & 7;
        const int g  = tid & 15;         // d*8 + wire
        const int d  = g >> 3, ww = g & 7;
        const float* th = theta + ((((tt * kNL + l) * kNB + uu) * 2 + d) * kNQ + ww) * 3;
        const float phi = th[0], tht = th[1], omg = th[2];
        float st, ct, sp, cp, sm, cm;
        fastsc(tht, st, ct);
        fastsc(phi + omg, sp, cp);
        fastsc(phi - omg, sm, cm);
        const float u00r =  ct * cp, u00i = -ct * sp;
        const float u01r = -st * cm, u01i = -st * sm;
        const float u10r =  st * cm, u10i = -st * sm;
        const float u11r =  ct * cp, u11i =  ct * sp;
        float* o = &gl[(l * kNB + uu) * kCircStride + g * kGateF];
        if (d == 1) {
            // h = g^dag Z g (Hermitian, traceless)
            o[0] = (u00r * u00r + u00i * u00i) - (u10r * u10r + u10i * u10i);
            o[1] = (u00r * u01r + u00i * u01i) - (u10r * u11r + u10i * u11i);
            o[2] = (u00r * u01i - u00i * u01r) - (u10r * u11i - u10i * u11r);
        } else {
            o[0] = u00r;  o[1] = u00i;
            o[2] = u01r;  o[3] = u01i;
            o[4] = u10r;  o[5] = u10i;
            o[6] = u11r;  o[7] = u11i;
        }
    }
    __syncthreads();

    // ---- phase 0: layer-0 circuit (t,u), angles from x ----
    float ang[8];
    {
        const float* ab = x + ((b * kT + tt) * kD + u * kNQ);
#pragma unroll
        for (int j = 0; j < 8; ++j) ang[j] = ab[j];
    }
    const float* base0 = &gl[u * kCircStride];
    float E = simdp(ang, base0, base0 + 8 * kGateF, mask);

    // ---- redistribute: layer-1 circuit u needs H0[t,b,i*8+u] = lane i*8+u ----
#pragma unroll
    for (int i = 0; i < 8; ++i) ang[i] = __shfl(E, i * 8 + u, 64);

    // ---- phase 1: layer-1 circuit (t,u) ----
    const float* base1 = &gl[(kNB + u) * kCircStride];
    E = simdp(ang, base1, base1 + 8 * kGateF, mask);

    out[(b * kT + tt) * kD + u * kNQ + w] = E;   // coalesced: 64 consecutive floats/wave
}

}  // namespace

extern "C" void kernel_launch(void* const* d_in, const int* in_sizes, int n_in,
                              void* d_out, int out_size, void* d_ws, size_t ws_size,
                              hipStream_t stream) {
    const float* x     = (const float*)d_in[0];   // (B, T, D) fp32
    const float* theta = (const float*)d_in[1];   // (T, NL, NB, DEPTH, NQ, 3) fp32
    float* out = (float*)d_out;                   // (B, T, D) fp32

    // single kernel: 8 timesteps x 256 samples = 2048 waves; 4 waves/block
    fused_kernel<<<kT * kB / 4, 256, 0, stream>>>(x, theta, out);
}